// Round 5
// baseline (104.086 us; speedup 1.0000x reference)
//
#include <hip/hip_runtime.h>

// Problem: B,H,W,D = 64,32,32,64 ; K=1024 ; N = 65536
#define NPTS   65536
#define DDIM   64
#define KCODES 1024
#define QOUT_ELEMS (NPTS * DDIM)

typedef _Float16 half8    __attribute__((ext_vector_type(8)));
typedef float    floatx16 __attribute__((ext_vector_type(16)));
typedef unsigned int uint;

// ws: ehp [0,128K) chunk-major f16 | elp [128K,256K) | e2 fp32 [256K,260K)
#define WS_EHP   0
#define WS_ELP   (128*1024)
#define WS_E2    (256*1024)

// ---------------------------------------------------------------------------
// Prep: one wave per code. fp16 hi/lo split, CHUNK-MAJOR tiles:
// tile T=k>>5, chunk j=d>>3, code-in-tile c=k&31:
//   byte off = T*4096 + j*512 + c*16 + (d&7)*2
// e2 (||e||^2) stored as plain fp32 (added post-MFMA, exact).
// ---------------------------------------------------------------------------
__global__ void eprep_kernel(const float* __restrict__ emb, char* __restrict__ ws) {
    const int tid = threadIdx.x;
    const int w = tid >> 6, d = tid & 63;
    const int k = blockIdx.x * 4 + w;
    float v = emb[(size_t)k * DDIM + d];
    _Float16 h = (_Float16)v;
    _Float16 l = (_Float16)(v - (float)h);
    size_t off = (size_t)(k >> 5) * 4096 + (size_t)(d >> 3) * 512
               + (size_t)(k & 31) * 16 + (size_t)(d & 7) * 2;
    *(_Float16*)(ws + WS_EHP + off) = h;
    *(_Float16*)(ws + WS_ELP + off) = l;
    float s = v * v;
    #pragma unroll
    for (int m = 1; m < 64; m <<= 1) s += __shfl_xor(s, m, 64);
    if (d == 0) ((float*)(ws + WS_E2))[k] = s;
}

// ---------------------------------------------------------------------------
// Main: grid 512, block 256 = 4 waves; wave w owns 32 points (pgrp*128+w*32+col)
// over the FULL K=1024 (32 tiles).
//
// Round-5 restructure: BARRIER-FREE main loop, register-resident B tiles.
// Evidence: per-SIMD wave-tile time was invariant to TLP (R2: 4 waves/SIMD
// 1850cy, R4: 2 waves/SIMD 1630cy) -> co-resident waves were fully
// serialized by barrier phase-lock. Fix: no LDS, no __syncthreads in the
// loop; each wave loads its own B fragments (1KB-contiguous coalesced loads,
// ws is L1/L2-resident) into a NAMED-regset double buffer (A/B), with
// sched_barrier(0) fences pinning LOADT(t+1) into TILE(t)'s region so the
// compiler cannot sink the prefetch to its use (R1's failure: VGPR=96
// proved the dbuf was dead). All waitcnts are compiler-derived from true
// data deps. Expected VGPR ~180 (2 waves/SIMD) -- that is the diagnostic.
//
// MFMA 32x32x16 f16 layouts (verified, absmax 0):
//   A[m][k]: m=lane&31, k=(lane>>5)*8+j ; B same with n=lane&31 ;
//   C/D: col=lane&31, row=(r&3)+8*(r>>2)+4*(lane>>5)
// ---------------------------------------------------------------------------
#define MFMA(A,B,C) __builtin_amdgcn_mfma_f32_32x32x16_f16(A,B,C,0,0,0)

__global__ __launch_bounds__(256, 2) void vq_kernel(
    const float* __restrict__ z,
    const char* __restrict__ ws_c,
    const float* __restrict__ emb,
    float* __restrict__ out)
{
    const int tid  = threadIdx.x;
    const int lane = tid & 63;
    const int w    = __builtin_amdgcn_readfirstlane(tid >> 6);
    const int col  = lane & 31;
    const int sel8 = lane >> 5;
    const int pgrp = blockIdx.x;

    __shared__ int s_final[128];

    // ---- A fragments: a = -2 z[pt], hi/lo fp16 ----
    const int pt = pgrp * 128 + w * 32 + col;
    half8 ah[4], al[4];
    {
        const float* zrow = z + (size_t)pt * DDIM + sel8 * 8;
        #pragma unroll
        for (int ks = 0; ks < 4; ++ks) {
            float4 u0 = *(const float4*)(zrow + ks * 16);
            float4 u1 = *(const float4*)(zrow + ks * 16 + 4);
            float tv[8] = {u0.x, u0.y, u0.z, u0.w, u1.x, u1.y, u1.z, u1.w};
            #pragma unroll
            for (int j = 0; j < 8; ++j) {
                float a = -2.0f * tv[j];
                _Float16 hh = (_Float16)a;
                ah[ks][j] = hh;
                al[ks][j] = (_Float16)(a - (float)hh);
            }
        }
    }

    const floatx16 zeroC = {};

    float best[16];
    int   bt[16];
    #pragma unroll
    for (int r = 0; r < 16; ++r) { best[r] = 3.4e38f; bt[r] = 0; }

    // Per-lane fragment base inside a tile (chunk-major layout):
    // wave reads 1KB contiguous per load (lanes 0..63 x 16B).
    const int myoff = sel8 * 512 + col * 16;
    const char*  ebase = ws_c + myoff;                 // + t*4096 + ks*1024
    const float* e2p   = (const float*)(ws_c + WS_E2); // fp32 ||e||^2

#define LOADT(BH, BL, E2, T) do {                                        \
    const char* _b = ebase + (size_t)(T) * 4096;                         \
    BH[0] = *(const half8*)(_b);                                         \
    BH[1] = *(const half8*)(_b + 1024);                                  \
    BH[2] = *(const half8*)(_b + 2048);                                  \
    BH[3] = *(const half8*)(_b + 3072);                                  \
    BL[0] = *(const half8*)(_b + WS_ELP);                                \
    BL[1] = *(const half8*)(_b + WS_ELP + 1024);                         \
    BL[2] = *(const half8*)(_b + WS_ELP + 2048);                         \
    BL[3] = *(const half8*)(_b + WS_ELP + 3072);                         \
    E2 = e2p[(T) * 32 + col];                                            \
} while (0)

#define TILE(T, BH, BL, E2) do {                                         \
    __builtin_amdgcn_s_setprio(1);                                       \
    floatx16 c0 = MFMA(ah[0], BH[0], zeroC);                             \
    floatx16 c1 = MFMA(ah[0], BL[0], zeroC);                             \
    c0 = MFMA(ah[1], BH[1], c0);  c1 = MFMA(ah[1], BL[1], c1);           \
    c0 = MFMA(ah[2], BH[2], c0);  c1 = MFMA(ah[2], BL[2], c1);           \
    c0 = MFMA(ah[3], BH[3], c0);  c1 = MFMA(ah[3], BL[3], c1);           \
    c0 = MFMA(al[0], BH[0], c0);  c1 = MFMA(al[2], BH[2], c1);           \
    c0 = MFMA(al[1], BH[1], c0);  c1 = MFMA(al[3], BH[3], c1);           \
    __builtin_amdgcn_s_setprio(0);                                       \
    _Pragma("unroll")                                                    \
    for (int r = 0; r < 16; ++r) {                                       \
        float d = (c0[r] + c1[r]) + (E2);                                \
        bool c = d < best[r];          /* strict <: earliest tile wins */ \
        best[r] = c ? d   : best[r];                                     \
        bt[r]   = c ? (T) : bt[r];                                       \
    }                                                                    \
} while (0)

    // Named regsets A/B (rule #20: no runtime-indexed register arrays).
    half8 bhA[4], blA[4], bhB[4], blB[4];
    float e2A, e2B;

    LOADT(bhA, blA, e2A, 0);
    #pragma unroll 1
    for (int t = 0; t < 32; t += 2) {
        // Region: issue prefetch(t+1) + compute(t). Fence stops the compiler
        // from sinking the B-set loads past TILE(t+1)'s first use.
        LOADT(bhB, blB, e2B, t + 1);
        TILE(t, bhA, blA, e2A);
        __builtin_amdgcn_sched_barrier(0);

        LOADT(bhA, blA, e2A, (t + 2) & 31);   // wrap: harmless reload at end
        TILE(t + 1, bhB, blB, e2B);
        __builtin_amdgcn_sched_barrier(0);
    }
#undef LOADT
#undef TILE

    // materialize codes; butterfly argmin across the 32 columns
    int code[16];
    #pragma unroll
    for (int r = 0; r < 16; ++r) code[r] = bt[r] * 32 + col;
    #pragma unroll
    for (int m = 1; m < 32; m <<= 1) {
        #pragma unroll
        for (int r = 0; r < 16; ++r) {
            float ov = __shfl_xor(best[r], m, 64);
            int   oc = __shfl_xor(code[r], m, 64);
            bool c = (ov < best[r]) || (ov == best[r] && oc < code[r]);
            best[r] = c ? ov : best[r];
            code[r] = c ? oc : code[r];
        }
    }
    if (col == 0) {   // lanes 0 and 32: 16 rows each
        #pragma unroll
        for (int r = 0; r < 16; ++r) {
            int row = (r & 3) + 8 * (r >> 2) + 4 * sel8;
            s_final[w * 32 + row] = code[r];
        }
    }
    __syncthreads();

    // indices (coalesced) + quantized gather: 128 pts x 16 float4
    if (tid < 128)
        out[QOUT_ELEMS + (size_t)pgrp * 128 + tid] = (float)s_final[tid];
    float4* outq = (float4*)out;
    const float4* emb4 = (const float4*)emb;
    #pragma unroll
    for (int it = 0; it < 8; ++it) {
        int f  = it * 256 + tid;
        int p  = f >> 4;
        int d4 = f & 15;
        int ks = s_final[p];
        outq[((size_t)pgrp * 128 + p) * (DDIM / 4) + d4] =
            emb4[(size_t)ks * (DDIM / 4) + d4];
    }
}

extern "C" void kernel_launch(void* const* d_in, const int* in_sizes, int n_in,
                              void* d_out, int out_size, void* d_ws, size_t ws_size,
                              hipStream_t stream) {
    const float* z   = (const float*)d_in[0];
    const float* emb = (const float*)d_in[1];
    float* out = (float*)d_out;
    char* ws = (char*)d_ws;

    eprep_kernel<<<KCODES / 4, 256, 0, stream>>>(emb, ws);
    vq_kernel<<<NPTS / 128, 256, 0, stream>>>(z, ws, emb, out);
}

// Round 6
// 99.782 us; speedup vs baseline: 1.0431x; 1.0431x over previous
//
#include <hip/hip_runtime.h>

// Problem: B,H,W,D = 64,32,32,64 ; K=1024 ; N = 65536
#define NPTS   65536
#define DDIM   64
#define KCODES 1024
#define QOUT_ELEMS (NPTS * DDIM)

typedef _Float16 half8    __attribute__((ext_vector_type(8)));
typedef float    floatx16 __attribute__((ext_vector_type(16)));
typedef unsigned int uint;

#define AS1 __attribute__((address_space(1)))
#define AS3 __attribute__((address_space(3)))

// ws: ehp [0,128K) chunk-major f16 | elp [128K,256K) | e2 fp32 [256K,260K)
#define WS_EHP   0
#define WS_ELP   (128*1024)
#define WS_E2    (256*1024)

static __device__ __forceinline__ void gl_lds16(const void* g, void* l) {
    __builtin_amdgcn_global_load_lds((const AS1 uint*)g, (AS3 uint*)l, 16, 0, 0);
}

// ---------------------------------------------------------------------------
// Prep: one wave per code. fp16 hi/lo split, CHUNK-MAJOR tiles:
// tile T=k>>5, chunk j=d>>3, code-in-tile c=k&31:
//   byte off = T*4096 + j*512 + c*16 + (d&7)*2
// e2 (||e||^2) stored as plain fp32 (added post-MFMA, exact).
// ---------------------------------------------------------------------------
__global__ void eprep_kernel(const float* __restrict__ emb, char* __restrict__ ws) {
    const int tid = threadIdx.x;
    const int w = tid >> 6, d = tid & 63;
    const int k = blockIdx.x * 4 + w;
    float v = emb[(size_t)k * DDIM + d];
    _Float16 h = (_Float16)v;
    _Float16 l = (_Float16)(v - (float)h);
    size_t off = (size_t)(k >> 5) * 4096 + (size_t)(d >> 3) * 512
               + (size_t)(k & 31) * 16 + (size_t)(d & 7) * 2;
    *(_Float16*)(ws + WS_EHP + off) = h;
    *(_Float16*)(ws + WS_ELP + off) = l;
    float s = v * v;
    #pragma unroll
    for (int m = 1; m < 64; m <<= 1) s += __shfl_xor(s, m, 64);
    if (d == 0) ((float*)(ws + WS_E2))[k] = s;
}

// ---------------------------------------------------------------------------
// Main: grid 512, block 256 = 4 waves; wave w owns 32 points (pgrp*128+w*32+col)
// over the FULL K=1024 (32 tiles).
//
// Round-6: T3+T4 deep pipeline. 4-deep LDS buffer ring, tiles staged THREE
// iterations ahead (~1800cy cover vs ~900cy worst-case HBM first-touch after
// the harness's 268MB L2/L3-thrashing re-poison). Counted s_waitcnt vmcnt(N)
// -- NEVER 0 in the main loop -- plus raw s_barrier (no __syncthreads: hipcc
// lowers it with a full vmcnt(0) drain that would kill the pipeline). READF
// one tile ahead into named regsets: COMP's lgkm deps were issued a full
// iteration (~700cy) earlier -> no lgkm stall. lgkmcnt(0) before each
// barrier guards LDS buffer reuse (my ds_reads retired before anyone
// overwrites that buffer). Prologue drains A-frag loads with vmcnt(0) so
// loop vmcnt counting only sees the 2 gl_lds ops/tile/wave.
// Accounting: in steady state 3 tiles x 2 ops = 6 in flight; retire the
// oldest tile -> vmcnt(4); tail: vmcnt(2), vmcnt(0).
//
// MFMA 32x32x16 f16 layouts (verified, absmax 0):
//   A[m][k]: m=lane&31, k=(lane>>5)*8+j ; B same with n=lane&31 ;
//   C/D: col=lane&31, row=(r&3)+8*(r>>2)+4*(lane>>5)
// MFMA cost is ~34 cy/instr PER SIMD (2382 TF uarch ceiling) -> per-tile
// matrix work ~410cy; MFMA-pipe floor for the whole kernel ~11us.
// ---------------------------------------------------------------------------
#define MFMA(A,B,C) __builtin_amdgcn_mfma_f32_32x32x16_f16(A,B,C,0,0,0)

__global__ __launch_bounds__(256, 2) void vq_kernel(
    const float* __restrict__ z,
    const char* __restrict__ ws_c,
    const float* __restrict__ emb,
    float* __restrict__ out)
{
    const int tid  = threadIdx.x;
    const int lane = tid & 63;
    const int w    = __builtin_amdgcn_readfirstlane(tid >> 6);
    const int col  = lane & 31;
    const int sel8 = lane >> 5;
    const int pgrp = blockIdx.x;

    __shared__ char  ebuf[4][8192];   // ring: [buf][eh 4KB | el 4KB] = 32KB
    __shared__ float lds_e2[1024];    // 4KB fp32 ||e||^2, all codes
    __shared__ int   s_final[128];

    // ---- A fragments: a = -2 z[pt], hi/lo fp16 ----
    const int pt = pgrp * 128 + w * 32 + col;
    half8 ah[4], al[4];
    {
        const float* zrow = z + (size_t)pt * DDIM + sel8 * 8;
        #pragma unroll
        for (int ks = 0; ks < 4; ++ks) {
            float4 u0 = *(const float4*)(zrow + ks * 16);
            float4 u1 = *(const float4*)(zrow + ks * 16 + 4);
            float tv[8] = {u0.x, u0.y, u0.z, u0.w, u1.x, u1.y, u1.z, u1.w};
            #pragma unroll
            for (int j = 0; j < 8; ++j) {
                float a = -2.0f * tv[j];
                _Float16 hh = (_Float16)a;
                ah[ks][j] = hh;
                al[ks][j] = (_Float16)(a - (float)hh);
            }
        }
    }
    // drain A-frag vmem so loop vmcnt accounting sees ONLY gl_lds ops
    asm volatile("s_waitcnt vmcnt(0)" ::: "memory");
    __builtin_amdgcn_sched_barrier(0);

    const floatx16 zeroC = {};

    float best[16];
    int   bt[16];
    #pragma unroll
    for (int r = 0; r < 16; ++r) { best[r] = 3.4e38f; bt[r] = 0; }

    // wave w stages 2KB/tile: operand = w>>1 (0=eh,1=el), half = w&1
    const int opnd = w >> 1, hsel = w & 1;
    const char* gsrc = ws_c + (opnd ? WS_ELP : WS_EHP) + hsel * 2048 + lane * 16;
    char* lbase = &ebuf[0][0] + opnd * 4096 + hsel * 2048;

#define STAGE(BUF, T) do {                                                    \
    const char* _s = gsrc + (size_t)(T) * 4096;                               \
    char* _d = lbase + (BUF) * 8192;                                          \
    gl_lds16(_s,        _d);                                                  \
    gl_lds16(_s + 1024, _d + 1024);                                           \
} while (0)

    const int myoff = sel8 * 512 + col * 16;   // chunk-major frag base in tile

#define READF(BUF, T, BH, BL, E2) do {                                        \
    const char* _b = &ebuf[BUF][0] + myoff;                                   \
    _Pragma("unroll")                                                         \
    for (int ks = 0; ks < 4; ++ks) {                                          \
        BH[ks] = *(const half8*)(_b + ks * 1024);                             \
        BL[ks] = *(const half8*)(_b + 4096 + ks * 1024);                      \
    }                                                                         \
    E2 = lds_e2[(T) * 32 + col];                                              \
} while (0)

#define COMP(T, BH, BL, E2) do {                                              \
    __builtin_amdgcn_s_setprio(1);                                            \
    floatx16 c0 = MFMA(ah[0], BH[0], zeroC);                                  \
    floatx16 c1 = MFMA(ah[0], BL[0], zeroC);                                  \
    c0 = MFMA(ah[1], BH[1], c0);  c1 = MFMA(ah[1], BL[1], c1);                \
    c0 = MFMA(ah[2], BH[2], c0);  c1 = MFMA(ah[2], BL[2], c1);                \
    c0 = MFMA(ah[3], BH[3], c0);  c1 = MFMA(ah[3], BL[3], c1);                \
    c0 = MFMA(al[0], BH[0], c0);  c1 = MFMA(al[2], BH[2], c1);                \
    c0 = MFMA(al[1], BH[1], c0);  c1 = MFMA(al[3], BH[3], c1);                \
    __builtin_amdgcn_s_setprio(0);                                            \
    _Pragma("unroll")                                                         \
    for (int r = 0; r < 16; ++r) {                                            \
        float d = (c0[r] + c1[r]) + (E2);                                     \
        bool c = d < best[r];          /* strict <: earliest tile wins */     \
        best[r] = c ? d   : best[r];                                          \
        bt[r]   = c ? (T) : bt[r];                                            \
    }                                                                         \
} while (0)

// counted wait + collective barrier. lgkmcnt(0): my ds_reads (issued a full
// COMP ago) retired before anyone overwrites that ring slot after the barrier.
#define WAITBAR(N) do {                                                       \
    asm volatile("s_waitcnt vmcnt(" #N ") lgkmcnt(0)" ::: "memory");          \
    __builtin_amdgcn_sched_barrier(0);                                        \
    __builtin_amdgcn_s_barrier();                                             \
    __builtin_amdgcn_sched_barrier(0);                                        \
} while (0)

    // Named regsets A/B (rule #20: no runtime-indexed register arrays).
    half8 bhA[4], blA[4], bhB[4], blB[4];
    float e2A, e2B;

    // -------- prologue: e2 + tiles 0..2 in flight (7 ops) --------
    gl_lds16(ws_c + WS_E2 + w * 1024 + lane * 16, (char*)lds_e2 + w * 1024);
    STAGE(0, 0);
    STAGE(1, 1);
    STAGE(2, 2);
    WAITBAR(4);                 // retire e2 + tile0 (3 oldest ops)
    READF(0, 0, bhA, blA, e2A);
    STAGE(3, 3);                // in flight: tiles 1,2,3 = 6 ops

    // -------- main loop: tiles 0..27, always 3 tiles ahead --------
    #pragma unroll 1
    for (int t = 0; t < 28; t += 2) {
        WAITBAR(4);                              // retire tile t+1
        READF((t + 1) & 3, t + 1, bhB, blB, e2B);
        STAGE((t + 4) & 3, t + 4);
        COMP(t, bhA, blA, e2A);

        WAITBAR(4);                              // retire tile t+2
        READF((t + 2) & 3, t + 2, bhA, blA, e2A);
        STAGE((t + 5) & 3, t + 5);
        COMP(t + 1, bhB, blB, e2B);
    }

    // -------- tail: tiles 28..31, draining the ring --------
    WAITBAR(4);                 // in flight {29,30,31}: retire 29
    READF(29 & 3, 29, bhB, blB, e2B);
    COMP(28, bhA, blA, e2A);

    WAITBAR(2);                 // in flight {30,31}: retire 30
    READF(30 & 3, 30, bhA, blA, e2A);
    COMP(29, bhB, blB, e2B);

    WAITBAR(0);                 // in flight {31}: retire 31
    READF(31 & 3, 31, bhB, blB, e2B);
    COMP(30, bhA, blA, e2A);

    COMP(31, bhB, blB, e2B);
#undef STAGE
#undef READF
#undef COMP
#undef WAITBAR

    // materialize codes; butterfly argmin across the 32 columns
    int code[16];
    #pragma unroll
    for (int r = 0; r < 16; ++r) code[r] = bt[r] * 32 + col;
    #pragma unroll
    for (int m = 1; m < 32; m <<= 1) {
        #pragma unroll
        for (int r = 0; r < 16; ++r) {
            float ov = __shfl_xor(best[r], m, 64);
            int   oc = __shfl_xor(code[r], m, 64);
            bool c = (ov < best[r]) || (ov == best[r] && oc < code[r]);
            best[r] = c ? ov : best[r];
            code[r] = c ? oc : code[r];
        }
    }
    if (col == 0) {   // lanes 0 and 32: 16 rows each
        #pragma unroll
        for (int r = 0; r < 16; ++r) {
            int row = (r & 3) + 8 * (r >> 2) + 4 * sel8;
            s_final[w * 32 + row] = code[r];
        }
    }
    __syncthreads();

    // indices (coalesced) + quantized gather: 128 pts x 16 float4
    if (tid < 128)
        out[QOUT_ELEMS + (size_t)pgrp * 128 + tid] = (float)s_final[tid];
    float4* outq = (float4*)out;
    const float4* emb4 = (const float4*)emb;
    #pragma unroll
    for (int it = 0; it < 8; ++it) {
        int f  = it * 256 + tid;
        int p  = f >> 4;
        int d4 = f & 15;
        int ks = s_final[p];
        outq[((size_t)pgrp * 128 + p) * (DDIM / 4) + d4] =
            emb4[(size_t)ks * (DDIM / 4) + d4];
    }
}

extern "C" void kernel_launch(void* const* d_in, const int* in_sizes, int n_in,
                              void* d_out, int out_size, void* d_ws, size_t ws_size,
                              hipStream_t stream) {
    const float* z   = (const float*)d_in[0];
    const float* emb = (const float*)d_in[1];
    float* out = (float*)d_out;
    char* ws = (char*)d_ws;

    eprep_kernel<<<KCODES / 4, 256, 0, stream>>>(emb, ws);
    vq_kernel<<<NPTS / 128, 256, 0, stream>>>(z, ws, emb, out);
}